// Round 12
// baseline (251.368 us; speedup 1.0000x reference)
//
#include <hip/hip_runtime.h>
#include <hip/hip_bf16.h>
#include <math.h>

#define B_ 4
#define T_ 2048
#define E_ 768
#define H_ 3
#define D_ 256
#define LOG2E 1.4426950408889634f

typedef __attribute__((ext_vector_type(8))) _Float16 half8;
typedef __attribute__((ext_vector_type(8))) unsigned short ushort8;
typedef __attribute__((ext_vector_type(4))) float f32x4;

static __device__ inline unsigned short f2h(float x) {
    _Float16 h = (_Float16)x;
    return *reinterpret_cast<unsigned short*>(&h);
}

#define GLOAD_LDS(SRC, DST) \
    __builtin_amdgcn_global_load_lds( \
        (const __attribute__((address_space(1))) void*)(SRC), \
        (__attribute__((address_space(3))) void*)(DST), 16, 0, 0)

// ---------------------------------------------------------------------------
// All weight transposes in ONE dispatch (validated R10/R11).
// ---------------------------------------------------------------------------
__global__ __launch_bounds__(256)
void transpose_cast_all(const float* __restrict__ Wk, const float* __restrict__ Wq,
                        const float* __restrict__ Wv, const float* __restrict__ Wo,
                        unsigned short* __restrict__ WTk, unsigned short* __restrict__ WTq,
                        unsigned short* __restrict__ WTv, unsigned short* __restrict__ WoT)
{
    __shared__ float tile[32][33];
    const int z = blockIdx.z;
    const float* in; unsigned short* out; int R, C;
    if (z < 9) {
        const int mat = z / 3, hd = z % 3;
        R = E_; C = D_;
        in  = (mat == 0 ? Wk  : mat == 1 ? Wq  : Wv)  + (long)hd * E_ * D_;
        out = (mat == 0 ? WTk : mat == 1 ? WTq : WTv) + (long)hd * D_ * E_;
    } else {
        R = E_; C = E_;
        in = Wo; out = WoT;
    }
    const int c0 = blockIdx.x * 32;
    const int r0 = blockIdx.y * 32;
    if (c0 >= C) return;
    const int t  = threadIdx.x;
    const int cc = t & 31, rr = t >> 5;
    #pragma unroll
    for (int i = 0; i < 4; ++i)
        tile[rr + i * 8][cc] = in[(long)(r0 + rr + i * 8) * C + c0 + cc];
    __syncthreads();
    const int rr2 = t & 31, cc2 = t >> 5;
    #pragma unroll
    for (int i = 0; i < 4; ++i)
        out[(long)(c0 + cc2 + i * 8) * R + r0 + rr2] = f2h(tile[rr2][cc2 + i * 8]);
}

// ---------------------------------------------------------------------------
// fp16 transpose (validated R6-R11).
// ---------------------------------------------------------------------------
__global__ __launch_bounds__(256)
void transpose16(const unsigned short* __restrict__ in, unsigned short* __restrict__ out,
                 int R, int Ccols)
{
    __shared__ unsigned short tile[64 * 64];
    char* tb = (char*)tile;
    const long zoff = (long)blockIdx.z * R * Ccols;
    const int r0 = blockIdx.y * 64, c0 = blockIdx.x * 64;
    const int t = threadIdx.x;
    #pragma unroll
    for (int i = 0; i < 2; ++i) {
        const int rr = (t >> 3) + i * 32;
        const int gc = (t & 7) * 8;
        ushort8 v = *(const ushort8*)(in + zoff + (long)(r0 + rr) * Ccols + c0 + gc);
        *(ushort8*)(tb + rr * 128 + ((gc * 2) ^ (((rr >> 3) & 7) << 4))) = v;
    }
    __syncthreads();
    #pragma unroll
    for (int i = 0; i < 2; ++i) {
        const int cc = (t >> 3) + i * 32;
        const int gr = (t & 7) * 8;
        ushort8 v;
        #pragma unroll
        for (int e = 0; e < 8; ++e) {
            const int row = gr + e;
            v[e] = *(const unsigned short*)(tb + row * 128 + ((cc * 2) ^ (((row >> 3) & 7) << 4)));
        }
        *(ushort8*)(out + zoff + (long)(c0 + cc) * R + r0 + gr) = v;
    }
}

// ---------------------------------------------------------------------------
// fp16 MFMA GEMM body (validated R6-R11).
// ---------------------------------------------------------------------------
template<bool CONVA, bool OUT16>
__device__ __forceinline__
void gemm_body(const float* Af, const unsigned short* Ah, const unsigned short* Bz,
               void* Cz, const float* bias, int K, int lda, int ldc,
               int m0, int n0, int tid)
{
    __shared__ unsigned short As[128 * 32];
    __shared__ unsigned short Bs[128 * 32];

    const int lane = tid & 63, wid = tid >> 6;
    const int wm = wid >> 1, wn = wid & 1;
    const int fr = lane & 15, fg = lane >> 4;

    f32x4 acc[4][4];
    #pragma unroll
    for (int mt = 0; mt < 4; ++mt)
        #pragma unroll
        for (int nt = 0; nt < 4; ++nt) acc[mt][nt] = (f32x4)(0.f);

    for (int k0 = 0; k0 < K; k0 += 32) {
        #pragma unroll
        for (int i = 0; i < 2; ++i) {
            const int G = tid + i * 256;
            const int row = G >> 2, g = G & 3;
            ushort8 pa;
            if (CONVA) {
                const float* s = Af + (long)(m0 + row) * lda + k0 + g * 8;
                float4 f0 = *(const float4*)s, f1 = *(const float4*)(s + 4);
                pa[0] = f2h(f0.x); pa[1] = f2h(f0.y); pa[2] = f2h(f0.z); pa[3] = f2h(f0.w);
                pa[4] = f2h(f1.x); pa[5] = f2h(f1.y); pa[6] = f2h(f1.z); pa[7] = f2h(f1.w);
            } else {
                pa = *(const ushort8*)(Ah + (long)(m0 + row) * lda + k0 + g * 8);
            }
            *(ushort8*)&As[row * 32 + g * 8] = pa;
            *(ushort8*)&Bs[row * 32 + g * 8] =
                *(const ushort8*)(Bz + (long)(n0 + row) * K + k0 + g * 8);
        }
        __syncthreads();

        half8 a[4], b[4];
        #pragma unroll
        for (int mt = 0; mt < 4; ++mt)
            a[mt] = *(const half8*)&As[(wm * 64 + mt * 16 + fr) * 32 + fg * 8];
        #pragma unroll
        for (int nt = 0; nt < 4; ++nt)
            b[nt] = *(const half8*)&Bs[(wn * 64 + nt * 16 + fr) * 32 + fg * 8];
        #pragma unroll
        for (int mt = 0; mt < 4; ++mt)
            #pragma unroll
            for (int nt = 0; nt < 4; ++nt)
                acc[mt][nt] = __builtin_amdgcn_mfma_f32_16x16x32_f16(
                                  a[mt], b[nt], acc[mt][nt], 0, 0, 0);
        __syncthreads();
    }

    #pragma unroll
    for (int nt = 0; nt < 4; ++nt) {
        const int col = n0 + wn * 64 + nt * 16 + fr;
        const float badd = bias ? bias[col] : 0.f;
        #pragma unroll
        for (int mt = 0; mt < 4; ++mt) {
            const int row = m0 + wm * 64 + mt * 16 + fg * 4;
            #pragma unroll
            for (int reg = 0; reg < 4; ++reg) {
                if (OUT16)
                    ((unsigned short*)Cz)[(long)(row + reg) * ldc + col] =
                        f2h(acc[mt][nt][reg] + badd);
                else
                    ((float*)Cz)[(long)(row + reg) * ldc + col] =
                        acc[mt][nt][reg] + badd;
            }
        }
    }
}

template<bool CONVA, bool OUT16>
__global__ __launch_bounds__(256)
void gemm_mfma(const void* __restrict__ Av, const unsigned short* __restrict__ Bt,
               void* __restrict__ Cv, const float* __restrict__ bias,
               int K, int Hdiv, int lda, int ldc, long sA, long sB, long sC)
{
    const int z = blockIdx.z;
    const float*          Af = (const float*)Av          + (long)(z / Hdiv) * sA;
    const unsigned short* Ah = (const unsigned short*)Av + (long)(z / Hdiv) * sA;
    const unsigned short* Bz = Bt + (long)(z % Hdiv) * sB;
    void* Cz = OUT16 ? (void*)((unsigned short*)Cv + (long)z * sC)
                     : (void*)((float*)Cv + (long)z * sC);
    gemm_body<CONVA, OUT16>(Af, Ah, Bz, Cz, bias, K, lda, ldc,
                            blockIdx.y * 128, blockIdx.x * 128, threadIdx.x);
}

__global__ __launch_bounds__(256)
void qkv_proj(const float* __restrict__ Xk, const float* __restrict__ Xv,
              const float* __restrict__ Xq,
              const unsigned short* __restrict__ WTk, const unsigned short* __restrict__ WTv,
              const unsigned short* __restrict__ WTq,
              unsigned short* __restrict__ Kp, unsigned short* __restrict__ Vp,
              unsigned short* __restrict__ Qp)
{
    const int z = blockIdx.z;
    const int which = z / 12, bh = z % 12;
    const int b = bh / H_, h = bh % H_;
    const float* X = (which == 0) ? Xk : (which == 1) ? Xv : Xq;
    const unsigned short* W = (which == 0) ? WTk : (which == 1) ? WTv : WTq;
    unsigned short* P = (which == 0) ? Kp : (which == 1) ? Vp : Qp;
    const float* Af = X + (long)b * T_ * E_;
    const unsigned short* Bz = W + (long)h * D_ * E_;
    unsigned short* Cz = P + (long)bh * T_ * D_;
    gemm_body<true, true>(Af, nullptr, Bz, Cz, nullptr, E_, E_, D_,
                          blockIdx.y * 128, blockIdx.x * 128, threadIdx.x);
}

// ---------------------------------------------------------------------------
// DUAL-STRIP wave-paired LDS-staged MFMA flash attention.
// Each wave owns TWO 16-row q-strips (32 rows): every K/V B-fragment LDS
// read is shared by 2 MFMAs -> LDS reads per q-row halve, and the strip-B
// compute overlaps strip-A's softmax/P-roundtrip latency (cross-strip ILP).
// Block = 4 waves x 32 rows = 128 q-rows as two 64-row tiles: waves 0,1 ->
// tile pi, waves 2,3 -> tile 31-pi (pi in [0,16)) -> grid 192 <= 256 CUs:
// NO CU sharing (R11's limiter: 2 blocks/CU doubled per-iter time).
// Staging/vmcnt/defer-max machinery unchanged from validated R11.
// Strip alignment (base % 32 == 0) guarantees no wave ever computes a
// fully-masked strip A -> defer-max NaN path impossible.
// XCD swizzle l=(p&7)*24+p/8: each XCD sees <=2 bh (4MB = one L2).
// ---------------------------------------------------------------------------
__global__ __launch_bounds__(256, 1)
void flash_dual(const unsigned short* __restrict__ Qb, const unsigned short* __restrict__ Kb,
                const unsigned short* __restrict__ Vtb, unsigned short* __restrict__ Z2h,
                float scale_log2e)
{
    __shared__ unsigned short Ktile[2][32 * 256];   // 16KB each
    __shared__ unsigned short Vtile[2][256 * 32];   // 16KB each
    __shared__ unsigned short Ps[4][16 * 72];       // 9KB

    const int p  = blockIdx.x;
    const int l  = (p & 7) * 24 + (p >> 3);    // 192 = 8*24, bijective
    const int bh = l >> 4;
    const int pi = l & 15;                     // 0..15
    const int b = bh / H_, h = bh % H_;
    const int tid = threadIdx.x;
    const int w = tid >> 6, lane = tid & 63;
    const int g = lane >> 4, fr = lane & 15;
    // wave's 32-row base: waves 0,1 -> 64-row tile pi; waves 2,3 -> tile 31-pi
    const int base = (w < 2) ? (pi * 64 + w * 32) : ((31 - pi) * 64 + (w - 2) * 32);

    const unsigned short* kg = Kb  + (long)bh * T_ * D_;
    const unsigned short* vg = Vtb + (long)bh * D_ * T_;

    // Q fragments for both strips (rows base+st*16+fr), exp2 domain
    const _Float16 hs = (_Float16)scale_log2e;
    half8 qf[2][8];
    #pragma unroll
    for (int st = 0; st < 2; ++st) {
        const unsigned short* qrow = Qb + ((long)bh * T_ + base + st * 16 + fr) * D_;
        #pragma unroll
        for (int c = 0; c < 8; ++c) {
            qf[st][c] = *(const half8*)(qrow + c * 32 + g * 8);
            qf[st][c] *= hs;
        }
    }

    f32x4 o[2][16];
    #pragma unroll
    for (int st = 0; st < 2; ++st)
        #pragma unroll
        for (int dt = 0; dt < 16; ++dt) o[st][dt] = (f32x4)(0.f);
    float mrow[2][4], lrow[2][4];
    #pragma unroll
    for (int st = 0; st < 2; ++st)
        #pragma unroll
        for (int reg = 0; reg < 4; ++reg) { mrow[st][reg] = -INFINITY; lrow[st][reg] = 0.f; }

    const int nkt = 2 * (31 - pi) + 2;         // k-tiles of 32

    auto STAGE = [&](int bufi, int kt) {
        const int k0 = kt * 32;
        #pragma unroll
        for (int i = 0; i < 4; ++i) {
            const int L = tid + i * 256;
            const int r = L >> 5, cg = L & 31;
            GLOAD_LDS(kg + (long)(k0 + r) * D_ + ((cg ^ (r & 7)) * 8),
                      &Ktile[bufi][L * 8]);
        }
        #pragma unroll
        for (int i = 0; i < 4; ++i) {
            const int L = tid + i * 256;
            const int dr = L >> 2, gq = L & 3;
            GLOAD_LDS(vg + (long)dr * T_ + k0 + ((gq ^ ((dr >> 1) & 3)) * 8),
                      &Vtile[bufi][L * 8]);
        }
    };

    STAGE(0, 0);
    int buf = 0;
    for (int kt = 0; kt < nkt; ++kt) {
        const bool pf_ = (kt + 1 < nkt);
        if (pf_) {
            STAGE(buf ^ 1, kt + 1);
            asm volatile("s_waitcnt vmcnt(8)" ::: "memory");
        } else {
            asm volatile("s_waitcnt vmcnt(0)" ::: "memory");
        }
        __builtin_amdgcn_sched_barrier(0);
        __builtin_amdgcn_s_barrier();
        __builtin_amdgcn_sched_barrier(0);

        const int k0 = kt * 32;
        if (k0 <= base + 31) {                   // wave live (strip B bound)
            // ---- QK^T both strips, shared kf reads ----
            f32x4 sA[2], sB[2];
            sA[0] = (f32x4)(0.f); sA[1] = (f32x4)(0.f);
            sB[0] = (f32x4)(0.f); sB[1] = (f32x4)(0.f);
            const int kkey = fr & 7;
            __builtin_amdgcn_s_setprio(1);
            #pragma unroll
            for (int c = 0; c < 8; ++c) {
                #pragma unroll
                for (int nt = 0; nt < 2; ++nt) {
                    const int kr = nt * 16 + fr;
                    half8 kf = *(const half8*)&Ktile[buf][(kr * 32 + ((c * 4 + g) ^ kkey)) * 8];
                    sA[nt] = __builtin_amdgcn_mfma_f32_16x16x32_f16(qf[0][c], kf, sA[nt], 0, 0, 0);
                    sB[nt] = __builtin_amdgcn_mfma_f32_16x16x32_f16(qf[1][c], kf, sB[nt], 0, 0, 0);
                }
            }
            __builtin_amdgcn_s_setprio(0);

            // ---- causal mask in place (log2 domain) ----
            #pragma unroll
            for (int nt = 0; nt < 2; ++nt)
                #pragma unroll
                for (int reg = 0; reg < 4; ++reg) {
                    const int kk = k0 + nt * 16 + fr;
                    if ((k0 + 31 > base)      && (kk > base + g * 4 + reg))      sA[nt][reg] = -INFINITY;
                    if ((k0 + 31 > base + 16) && (kk > base + 16 + g * 4 + reg)) sB[nt][reg] = -INFINITY;
                }

            // ---- defer-max: one ballot over both strips ----
            float pmA[4], pmB[4];
            #pragma unroll
            for (int reg = 0; reg < 4; ++reg) {
                pmA[reg] = fmaxf(sA[0][reg], sA[1][reg]);
                pmB[reg] = fmaxf(sB[0][reg], sB[1][reg]);
            }
            const bool ok = (pmA[0] <= mrow[0][0] + 8.f) && (pmA[1] <= mrow[0][1] + 8.f)
                         && (pmA[2] <= mrow[0][2] + 8.f) && (pmA[3] <= mrow[0][3] + 8.f)
                         && (pmB[0] <= mrow[1][0] + 8.f) && (pmB[1] <= mrow[1][1] + 8.f)
                         && (pmB[2] <= mrow[1][2] + 8.f) && (pmB[3] <= mrow[1][3] + 8.f);
            if (!__all(ok)) {
                #pragma unroll
                for (int st = 0; st < 2; ++st)
                    #pragma unroll
                    for (int reg = 0; reg < 4; ++reg) {
                        float tm = st ? pmB[reg] : pmA[reg];
                        tm = fmaxf(tm, __shfl_xor(tm, 1));
                        tm = fmaxf(tm, __shfl_xor(tm, 2));
                        tm = fmaxf(tm, __shfl_xor(tm, 4));
                        tm = fmaxf(tm, __shfl_xor(tm, 8));
                        const float mnew = fmaxf(mrow[st][reg], tm);
                        const float alpha = exp2f(mrow[st][reg] - mnew);
                        mrow[st][reg] = mnew;
                        lrow[st][reg] *= alpha;
                        #pragma unroll
                        for (int dt = 0; dt < 16; ++dt) o[st][dt][reg] *= alpha;
                    }
            }

            // ---- pp + Ps + A-frag, strip A then strip B (Ps reused; DS in-order) ----
            half8 pfr[2];
            #pragma unroll
            for (int st = 0; st < 2; ++st) {
                #pragma unroll
                for (int nt = 0; nt < 2; ++nt)
                    #pragma unroll
                    for (int reg = 0; reg < 4; ++reg) {
                        const float svv = st ? sB[nt][reg] : sA[nt][reg];
                        const float pp = exp2f(svv - mrow[st][reg]);
                        lrow[st][reg] += pp;
                        Ps[w][(g * 4 + reg) * 72 + nt * 16 + fr] = f2h(pp);
                    }
                pfr[st] = *(const half8*)&Ps[w][fr * 72 + g * 8];
            }

            // ---- PV both strips, shared vf reads ----
            const int vkey = g ^ ((fr >> 1) & 3);
            __builtin_amdgcn_s_setprio(1);
            #pragma unroll
            for (int dt = 0; dt < 16; ++dt) {
                const int dr = dt * 16 + fr;
                half8 vf = *(const half8*)&Vtile[buf][(dr * 4 + vkey) * 8];
                o[0][dt] = __builtin_amdgcn_mfma_f32_16x16x32_f16(pfr[0], vf, o[0][dt], 0, 0, 0);
                o[1][dt] = __builtin_amdgcn_mfma_f32_16x16x32_f16(pfr[1], vf, o[1][dt], 0, 0, 0);
            }
            __builtin_amdgcn_s_setprio(0);
        }
        __builtin_amdgcn_sched_barrier(0);
        __builtin_amdgcn_s_barrier();
        buf ^= 1;
    }

    // ---- epilogue per strip: reduce lrow, O /= l, write f16 ----
    #pragma unroll
    for (int st = 0; st < 2; ++st) {
        float inv[4];
        #pragma unroll
        for (int reg = 0; reg < 4; ++reg) {
            float ps = lrow[st][reg];
            ps += __shfl_xor(ps, 1);
            ps += __shfl_xor(ps, 2);
            ps += __shfl_xor(ps, 4);
            ps += __shfl_xor(ps, 8);
            inv[reg] = 1.f / ps;
        }
        const long rowbase = ((long)b * T_ + base + st * 16 + g * 4) * E_ + h * D_;
        #pragma unroll
        for (int reg = 0; reg < 4; ++reg) {
            unsigned short* dst = Z2h + rowbase + (long)reg * E_ + fr;
            #pragma unroll
            for (int dt = 0; dt < 16; ++dt)
                dst[dt * 16] = f2h(o[st][dt][reg] * inv[reg]);
        }
    }
}

// ---------------------------------------------------------------------------
// d_in: keys, values, queries, Wk, Wq, Wv, Wo, bo (fp32)
// ws (f16): Kp|Vp|Qp|Vt (4 x 12.6MB) | Z2h 12.6MB | WTk|WTq|WTv|WoT 4.7MB
// ---------------------------------------------------------------------------
extern "C" void kernel_launch(void* const* d_in, const int* in_sizes, int n_in,
                              void* d_out, int out_size, void* d_ws, size_t ws_size,
                              hipStream_t stream)
{
    const float* Xk = (const float*)d_in[0];
    const float* Xv = (const float*)d_in[1];
    const float* Xq = (const float*)d_in[2];
    const float* Wk = (const float*)d_in[3];
    const float* Wq = (const float*)d_in[4];
    const float* Wv = (const float*)d_in[5];
    const float* Wo = (const float*)d_in[6];
    const float* bo = (const float*)d_in[7];
    float* out = (float*)d_out;

    const size_t phd = (size_t)B_ * H_ * T_ * D_;   // 6,291,456
    const size_t wsz = (size_t)H_ * E_ * D_;        // 589,824
    unsigned short* Kp  = (unsigned short*)d_ws;
    unsigned short* Vp  = Kp + phd;
    unsigned short* Qp  = Vp + phd;
    unsigned short* Vt  = Qp + phd;
    unsigned short* Z2h = Vt + phd;
    unsigned short* WTk = Z2h + (size_t)B_ * T_ * E_;
    unsigned short* WTq = WTk + wsz;
    unsigned short* WTv = WTq + wsz;
    unsigned short* WoT = WTv + wsz;

    dim3 blk(256);

    dim3 gtw(E_ / 32, E_ / 32, 10);
    transpose_cast_all<<<gtw, blk, 0, stream>>>(Wk, Wq, Wv, Wo, WTk, WTq, WTv, WoT);

    dim3 gproj(D_ / 128, T_ / 128, 36);
    qkv_proj<<<gproj, blk, 0, stream>>>(Xk, Xv, Xq, WTk, WTv, WTq, Kp, Vp, Qp);

    dim3 gtv(D_ / 64, T_ / 64, B_ * H_);
    transpose16<<<gtv, blk, 0, stream>>>(Vp, Vt, T_, D_);

    // Dual-strip flash: 192 blocks (16 pi x 12 bh), 4 waves x 32 q-rows
    dim3 gf(16 * B_ * H_);
    flash_dual<<<gf, blk, 0, stream>>>(Qp, Kp, Vt, Z2h,
                                       0.022097086912079608f * LOG2E);

    dim3 gout(E_ / 128, (B_ * T_) / 128, 1);
    gemm_mfma<false, false><<<gout, blk, 0, stream>>>(Z2h, WoT, out, bo, E_, 1, E_, E_,
                                                      0L, 0L, 0L);
}

// Round 13
// 202.038 us; speedup vs baseline: 1.2442x; 1.2442x over previous
//
#include <hip/hip_runtime.h>
#include <hip/hip_bf16.h>
#include <math.h>

#define B_ 4
#define T_ 2048
#define E_ 768
#define H_ 3
#define D_ 256
#define LOG2E 1.4426950408889634f

typedef __attribute__((ext_vector_type(8))) _Float16 half8;
typedef __attribute__((ext_vector_type(8))) unsigned short ushort8;
typedef __attribute__((ext_vector_type(4))) float f32x4;

static __device__ inline unsigned short f2h(float x) {
    _Float16 h = (_Float16)x;
    return *reinterpret_cast<unsigned short*>(&h);
}

#define GLOAD_LDS(SRC, DST) \
    __builtin_amdgcn_global_load_lds( \
        (const __attribute__((address_space(1))) void*)(SRC), \
        (__attribute__((address_space(3))) void*)(DST), 16, 0, 0)

// ---------------------------------------------------------------------------
// All weight transposes in ONE dispatch (validated R10/R11).
// ---------------------------------------------------------------------------
__global__ __launch_bounds__(256)
void transpose_cast_all(const float* __restrict__ Wk, const float* __restrict__ Wq,
                        const float* __restrict__ Wv, const float* __restrict__ Wo,
                        unsigned short* __restrict__ WTk, unsigned short* __restrict__ WTq,
                        unsigned short* __restrict__ WTv, unsigned short* __restrict__ WoT)
{
    __shared__ float tile[32][33];
    const int z = blockIdx.z;
    const float* in; unsigned short* out; int R, C;
    if (z < 9) {
        const int mat = z / 3, hd = z % 3;
        R = E_; C = D_;
        in  = (mat == 0 ? Wk  : mat == 1 ? Wq  : Wv)  + (long)hd * E_ * D_;
        out = (mat == 0 ? WTk : mat == 1 ? WTq : WTv) + (long)hd * D_ * E_;
    } else {
        R = E_; C = E_;
        in = Wo; out = WoT;
    }
    const int c0 = blockIdx.x * 32;
    const int r0 = blockIdx.y * 32;
    if (c0 >= C) return;
    const int t  = threadIdx.x;
    const int cc = t & 31, rr = t >> 5;
    #pragma unroll
    for (int i = 0; i < 4; ++i)
        tile[rr + i * 8][cc] = in[(long)(r0 + rr + i * 8) * C + c0 + cc];
    __syncthreads();
    const int rr2 = t & 31, cc2 = t >> 5;
    #pragma unroll
    for (int i = 0; i < 4; ++i)
        out[(long)(c0 + cc2 + i * 8) * R + r0 + rr2] = f2h(tile[rr2][cc2 + i * 8]);
}

// ---------------------------------------------------------------------------
// fp16 transpose (validated R6-R12).
// ---------------------------------------------------------------------------
__global__ __launch_bounds__(256)
void transpose16(const unsigned short* __restrict__ in, unsigned short* __restrict__ out,
                 int R, int Ccols)
{
    __shared__ unsigned short tile[64 * 64];
    char* tb = (char*)tile;
    const long zoff = (long)blockIdx.z * R * Ccols;
    const int r0 = blockIdx.y * 64, c0 = blockIdx.x * 64;
    const int t = threadIdx.x;
    #pragma unroll
    for (int i = 0; i < 2; ++i) {
        const int rr = (t >> 3) + i * 32;
        const int gc = (t & 7) * 8;
        ushort8 v = *(const ushort8*)(in + zoff + (long)(r0 + rr) * Ccols + c0 + gc);
        *(ushort8*)(tb + rr * 128 + ((gc * 2) ^ (((rr >> 3) & 7) << 4))) = v;
    }
    __syncthreads();
    #pragma unroll
    for (int i = 0; i < 2; ++i) {
        const int cc = (t >> 3) + i * 32;
        const int gr = (t & 7) * 8;
        ushort8 v;
        #pragma unroll
        for (int e = 0; e < 8; ++e) {
            const int row = gr + e;
            v[e] = *(const unsigned short*)(tb + row * 128 + ((cc * 2) ^ (((row >> 3) & 7) << 4)));
        }
        *(ushort8*)(out + zoff + (long)(c0 + cc) * R + r0 + gr) = v;
    }
}

// ---------------------------------------------------------------------------
// fp16 MFMA GEMM body (validated R6-R12).
// ---------------------------------------------------------------------------
template<bool CONVA, bool OUT16>
__device__ __forceinline__
void gemm_body(const float* Af, const unsigned short* Ah, const unsigned short* Bz,
               void* Cz, const float* bias, int K, int lda, int ldc,
               int m0, int n0, int tid)
{
    __shared__ unsigned short As[128 * 32];
    __shared__ unsigned short Bs[128 * 32];

    const int lane = tid & 63, wid = tid >> 6;
    const int wm = wid >> 1, wn = wid & 1;
    const int fr = lane & 15, fg = lane >> 4;

    f32x4 acc[4][4];
    #pragma unroll
    for (int mt = 0; mt < 4; ++mt)
        #pragma unroll
        for (int nt = 0; nt < 4; ++nt) acc[mt][nt] = (f32x4)(0.f);

    for (int k0 = 0; k0 < K; k0 += 32) {
        #pragma unroll
        for (int i = 0; i < 2; ++i) {
            const int G = tid + i * 256;
            const int row = G >> 2, g = G & 3;
            ushort8 pa;
            if (CONVA) {
                const float* s = Af + (long)(m0 + row) * lda + k0 + g * 8;
                float4 f0 = *(const float4*)s, f1 = *(const float4*)(s + 4);
                pa[0] = f2h(f0.x); pa[1] = f2h(f0.y); pa[2] = f2h(f0.z); pa[3] = f2h(f0.w);
                pa[4] = f2h(f1.x); pa[5] = f2h(f1.y); pa[6] = f2h(f1.z); pa[7] = f2h(f1.w);
            } else {
                pa = *(const ushort8*)(Ah + (long)(m0 + row) * lda + k0 + g * 8);
            }
            *(ushort8*)&As[row * 32 + g * 8] = pa;
            *(ushort8*)&Bs[row * 32 + g * 8] =
                *(const ushort8*)(Bz + (long)(n0 + row) * K + k0 + g * 8);
        }
        __syncthreads();

        half8 a[4], b[4];
        #pragma unroll
        for (int mt = 0; mt < 4; ++mt)
            a[mt] = *(const half8*)&As[(wm * 64 + mt * 16 + fr) * 32 + fg * 8];
        #pragma unroll
        for (int nt = 0; nt < 4; ++nt)
            b[nt] = *(const half8*)&Bs[(wn * 64 + nt * 16 + fr) * 32 + fg * 8];
        #pragma unroll
        for (int mt = 0; mt < 4; ++mt)
            #pragma unroll
            for (int nt = 0; nt < 4; ++nt)
                acc[mt][nt] = __builtin_amdgcn_mfma_f32_16x16x32_f16(
                                  a[mt], b[nt], acc[mt][nt], 0, 0, 0);
        __syncthreads();
    }

    #pragma unroll
    for (int nt = 0; nt < 4; ++nt) {
        const int col = n0 + wn * 64 + nt * 16 + fr;
        const float badd = bias ? bias[col] : 0.f;
        #pragma unroll
        for (int mt = 0; mt < 4; ++mt) {
            const int row = m0 + wm * 64 + mt * 16 + fg * 4;
            #pragma unroll
            for (int reg = 0; reg < 4; ++reg) {
                if (OUT16)
                    ((unsigned short*)Cz)[(long)(row + reg) * ldc + col] =
                        f2h(acc[mt][nt][reg] + badd);
                else
                    ((float*)Cz)[(long)(row + reg) * ldc + col] =
                        acc[mt][nt][reg] + badd;
            }
        }
    }
}

template<bool CONVA, bool OUT16>
__global__ __launch_bounds__(256)
void gemm_mfma(const void* __restrict__ Av, const unsigned short* __restrict__ Bt,
               void* __restrict__ Cv, const float* __restrict__ bias,
               int K, int Hdiv, int lda, int ldc, long sA, long sB, long sC)
{
    const int z = blockIdx.z;
    const float*          Af = (const float*)Av          + (long)(z / Hdiv) * sA;
    const unsigned short* Ah = (const unsigned short*)Av + (long)(z / Hdiv) * sA;
    const unsigned short* Bz = Bt + (long)(z % Hdiv) * sB;
    void* Cz = OUT16 ? (void*)((unsigned short*)Cv + (long)z * sC)
                     : (void*)((float*)Cv + (long)z * sC);
    gemm_body<CONVA, OUT16>(Af, Ah, Bz, Cz, bias, K, lda, ldc,
                            blockIdx.y * 128, blockIdx.x * 128, threadIdx.x);
}

__global__ __launch_bounds__(256)
void qkv_proj(const float* __restrict__ Xk, const float* __restrict__ Xv,
              const float* __restrict__ Xq,
              const unsigned short* __restrict__ WTk, const unsigned short* __restrict__ WTv,
              const unsigned short* __restrict__ WTq,
              unsigned short* __restrict__ Kp, unsigned short* __restrict__ Vp,
              unsigned short* __restrict__ Qp)
{
    const int z = blockIdx.z;
    const int which = z / 12, bh = z % 12;
    const int b = bh / H_, h = bh % H_;
    const float* X = (which == 0) ? Xk : (which == 1) ? Xv : Xq;
    const unsigned short* W = (which == 0) ? WTk : (which == 1) ? WTv : WTq;
    unsigned short* P = (which == 0) ? Kp : (which == 1) ? Vp : Qp;
    const float* Af = X + (long)b * T_ * E_;
    const unsigned short* Bz = W + (long)h * D_ * E_;
    unsigned short* Cz = P + (long)bh * T_ * D_;
    gemm_body<true, true>(Af, nullptr, Bz, Cz, nullptr, E_, E_, D_,
                          blockIdx.y * 128, blockIdx.x * 128, threadIdx.x);
}

// ---------------------------------------------------------------------------
// Wave-paired LDS-staged MFMA flash attention (R11 structure, 114us) with
// SINGLE-BARRIER pipeline windows. Per window:
//   [s_waitcnt vmcnt(0)  -> my tile-t loads done (only ones in flight)]
//   [s_barrier           -> all waves drained: tile t fully visible; also
//                           proves everyone finished computing buf^1]
//   [STAGE(buf^1, t+1)   -> safe overwrite; loads overlap compute of t]
//   [compute(buf)]
// One barrier per window vs R11's two; same counted-prefetch overlap.
// Defer-max softmax (THR=8) + per-lane deferred l-reduce (validated R11).
// Grid 384 = 32 pi x 12 bh, wave-paired (waves 0,1 -> tile pi; 2,3 -> 63-pi)
// -> uniform 130 active wave-iters/block; 2 blocks/CU, 8 waves/CU.
// ---------------------------------------------------------------------------
__global__ __launch_bounds__(256, 2)
void flash_lds(const unsigned short* __restrict__ Qb, const unsigned short* __restrict__ Kb,
               const unsigned short* __restrict__ Vtb, unsigned short* __restrict__ Z2h,
               float scale_log2e)
{
    __shared__ unsigned short Ktile[2][32 * 256];   // 16KB each
    __shared__ unsigned short Vtile[2][256 * 32];   // 16KB each
    __shared__ unsigned short Ps[4][16 * 72];       // 9KB

    const int p  = blockIdx.x;
    const int bh = p % 12;
    const int pi = p / 12;                     // 0..31
    const int qtB = 63 - pi;
    const int b = bh / H_, h = bh % H_;
    const int tid = threadIdx.x;
    const int w = tid >> 6, lane = tid & 63;
    const int g = lane >> 4, fr = lane & 15;
    const int qw0 = (w < 2) ? (pi * 32 + w * 16) : (qtB * 32 + (w - 2) * 16);

    const unsigned short* kg = Kb  + (long)bh * T_ * D_;
    const unsigned short* vg = Vtb + (long)bh * D_ * T_;

    const unsigned short* qrow = Qb + ((long)bh * T_ + qw0 + fr) * D_;
    const _Float16 hs = (_Float16)scale_log2e;
    half8 qf[8];
    #pragma unroll
    for (int c = 0; c < 8; ++c) {
        qf[c] = *(const half8*)(qrow + c * 32 + g * 8);
        qf[c] *= hs;
    }

    f32x4 o[16];
    #pragma unroll
    for (int dt = 0; dt < 16; ++dt) o[dt] = (f32x4)(0.f);
    float mrow[4] = {-INFINITY, -INFINITY, -INFINITY, -INFINITY};
    float lrow[4] = {0.f, 0.f, 0.f, 0.f};     // per-lane partials (deferred reduce)

    const int nkt = qtB + 1;

    auto STAGE = [&](int bufi, int kt) {
        const int k0 = kt * 32;
        #pragma unroll
        for (int i = 0; i < 4; ++i) {
            const int L = tid + i * 256;
            const int r = L >> 5, cg = L & 31;
            GLOAD_LDS(kg + (long)(k0 + r) * D_ + ((cg ^ (r & 7)) * 8),
                      &Ktile[bufi][L * 8]);
        }
        #pragma unroll
        for (int i = 0; i < 4; ++i) {
            const int L = tid + i * 256;
            const int dr = L >> 2, gq = L & 3;
            GLOAD_LDS(vg + (long)dr * T_ + k0 + ((gq ^ ((dr >> 1) & 3)) * 8),
                      &Vtile[bufi][L * 8]);
        }
    };

    STAGE(0, 0);
    int buf = 0;
    for (int kt = 0; kt < nkt; ++kt) {
        asm volatile("s_waitcnt vmcnt(0)" ::: "memory");    // my tile-t loads
        __builtin_amdgcn_sched_barrier(0);
        __builtin_amdgcn_s_barrier();                        // all waves drained
        __builtin_amdgcn_sched_barrier(0);
        if (kt + 1 < nkt)
            STAGE(buf ^ 1, kt + 1);                          // overlaps compute(t)

        const int k0 = kt * 32;
        if (k0 <= qw0 + 15) {
            // ---- QK^T: S[16q x 32k] ----
            f32x4 s[2];
            s[0] = (f32x4)(0.f); s[1] = (f32x4)(0.f);
            const int kkey = fr & 7;
            __builtin_amdgcn_s_setprio(1);
            #pragma unroll
            for (int c = 0; c < 8; ++c) {
                #pragma unroll
                for (int nt = 0; nt < 2; ++nt) {
                    const int kr = nt * 16 + fr;
                    half8 kf = *(const half8*)&Ktile[buf][(kr * 32 + ((c * 4 + g) ^ kkey)) * 8];
                    s[nt] = __builtin_amdgcn_mfma_f32_16x16x32_f16(qf[c], kf, s[nt], 0, 0, 0);
                }
            }
            __builtin_amdgcn_s_setprio(0);

            // ---- causal mask (log2 domain) ----
            const bool diag = (k0 + 31 > qw0);
            float sv[2][4];
            #pragma unroll
            for (int nt = 0; nt < 2; ++nt)
                #pragma unroll
                for (int reg = 0; reg < 4; ++reg) {
                    float v = s[nt][reg];
                    if (diag && (k0 + nt * 16 + fr > qw0 + g * 4 + reg)) v = -INFINITY;
                    sv[nt][reg] = v;
                }

            // ---- defer-max online softmax ----
            float pmax[4];
            #pragma unroll
            for (int reg = 0; reg < 4; ++reg) pmax[reg] = fmaxf(sv[0][reg], sv[1][reg]);
            const bool ok = (pmax[0] <= mrow[0] + 8.f) && (pmax[1] <= mrow[1] + 8.f)
                         && (pmax[2] <= mrow[2] + 8.f) && (pmax[3] <= mrow[3] + 8.f);
            if (!__all(ok)) {
                #pragma unroll
                for (int reg = 0; reg < 4; ++reg) {
                    float tm = pmax[reg];
                    tm = fmaxf(tm, __shfl_xor(tm, 1));
                    tm = fmaxf(tm, __shfl_xor(tm, 2));
                    tm = fmaxf(tm, __shfl_xor(tm, 4));
                    tm = fmaxf(tm, __shfl_xor(tm, 8));
                    const float mnew = fmaxf(mrow[reg], tm);
                    const float alpha = exp2f(mrow[reg] - mnew);
                    mrow[reg] = mnew;
                    lrow[reg] *= alpha;
                    #pragma unroll
                    for (int dt = 0; dt < 16; ++dt) o[dt][reg] *= alpha;
                }
            }
            #pragma unroll
            for (int nt = 0; nt < 2; ++nt)
                #pragma unroll
                for (int reg = 0; reg < 4; ++reg) {
                    const float pp = exp2f(sv[nt][reg] - mrow[reg]);
                    lrow[reg] += pp;
                    Ps[w][(g * 4 + reg) * 72 + nt * 16 + fr] = f2h(pp);
                }

            // ---- P as A-frag ----
            const half8 pf0 = *(const half8*)&Ps[w][fr * 72 + g * 8];

            // ---- PV: O[16q x 256d] += P * V ----
            const int vkey = g ^ ((fr >> 1) & 3);
            __builtin_amdgcn_s_setprio(1);
            #pragma unroll
            for (int dt = 0; dt < 16; ++dt) {
                const int dr = dt * 16 + fr;
                half8 vf = *(const half8*)&Vtile[buf][(dr * 4 + vkey) * 8];
                o[dt] = __builtin_amdgcn_mfma_f32_16x16x32_f16(pf0, vf, o[dt], 0, 0, 0);
            }
            __builtin_amdgcn_s_setprio(0);
        }
        buf ^= 1;
    }

    // ---- epilogue: reduce lrow across fr lanes, O /= l, write f16 ----
    float inv[4];
    #pragma unroll
    for (int reg = 0; reg < 4; ++reg) {
        float ps = lrow[reg];
        ps += __shfl_xor(ps, 1);
        ps += __shfl_xor(ps, 2);
        ps += __shfl_xor(ps, 4);
        ps += __shfl_xor(ps, 8);
        inv[reg] = 1.f / ps;
    }
    const long rowbase = ((long)b * T_ + qw0 + g * 4) * E_ + h * D_;
    #pragma unroll
    for (int reg = 0; reg < 4; ++reg) {
        unsigned short* dst = Z2h + rowbase + (long)reg * E_ + fr;
        #pragma unroll
        for (int dt = 0; dt < 16; ++dt)
            dst[dt * 16] = f2h(o[dt][reg] * inv[reg]);
    }
}

// ---------------------------------------------------------------------------
// d_in: keys, values, queries, Wk, Wq, Wv, Wo, bo (fp32)
// ws (f16): Kp|Vp|Qp|Vt (4 x 12.6MB) | Z2h 12.6MB | WTk|WTq|WTv|WoT 4.7MB
// ---------------------------------------------------------------------------
extern "C" void kernel_launch(void* const* d_in, const int* in_sizes, int n_in,
                              void* d_out, int out_size, void* d_ws, size_t ws_size,
                              hipStream_t stream)
{
    const float* Xk = (const float*)d_in[0];
    const float* Xv = (const float*)d_in[1];
    const float* Xq = (const float*)d_in[2];
    const float* Wk = (const float*)d_in[3];
    const float* Wq = (const float*)d_in[4];
    const float* Wv = (const float*)d_in[5];
    const float* Wo = (const float*)d_in[6];
    const float* bo = (const float*)d_in[7];
    float* out = (float*)d_out;

    const size_t phd = (size_t)B_ * H_ * T_ * D_;   // 6,291,456
    const size_t wsz = (size_t)H_ * E_ * D_;        // 589,824
    unsigned short* Kp  = (unsigned short*)d_ws;
    unsigned short* Vp  = Kp + phd;
    unsigned short* Qp  = Vp + phd;
    unsigned short* Vt  = Qp + phd;
    unsigned short* Z2h = Vt + phd;
    unsigned short* WTk = Z2h + (size_t)B_ * T_ * E_;
    unsigned short* WTq = WTk + wsz;
    unsigned short* WTv = WTq + wsz;
    unsigned short* WoT = WTv + wsz;

    dim3 blk(256);

    dim3 gtw(E_ / 32, E_ / 32, 10);
    transpose_cast_all<<<gtw, blk, 0, stream>>>(Wk, Wq, Wv, Wo, WTk, WTq, WTv, WoT);

    dim3 gproj(D_ / 128, T_ / 128, 36);
    qkv_proj<<<gproj, blk, 0, stream>>>(Xk, Xv, Xq, WTk, WTv, WTq, Kp, Vp, Qp);

    dim3 gtv(D_ / 64, T_ / 64, B_ * H_);
    transpose16<<<gtv, blk, 0, stream>>>(Vp, Vt, T_, D_);

    dim3 gf(32 * B_ * H_);                          // 384 uniform blocks x 4 waves
    flash_lds<<<gf, blk, 0, stream>>>(Qp, Kp, Vt, Z2h,
                                      0.022097086912079608f * LOG2E);

    dim3 gout(E_ / 128, (B_ * T_) / 128, 1);
    gemm_mfma<false, false><<<gout, blk, 0, stream>>>(Z2h, WoT, out, bo, E_, 1, E_, E_,
                                                      0L, 0L, 0L);
}